// Round 6
// baseline (261.994 us; speedup 1.0000x reference)
//
#include <hip/hip_runtime.h>
#include <hip/hip_bf16.h>
#include <math.h>

#define NB 16
#define RB 64
#define HB 128
#define WB 128
#define DB 256
#define HW (HB * WB)

typedef __attribute__((ext_vector_type(8))) short bf16x8;
typedef __attribute__((ext_vector_type(4))) float f32x4;

static __device__ __forceinline__ short f2bf(float f) {
  __hip_bfloat16 h = __float2bfloat16(f);
  return *reinterpret_cast<short*>(&h);
}

// async global->LDS, 16B per lane: HW writes wave-uniform LDS base + lane*16
#define GLOAD_LDS16(gp, lp)                                          \
  __builtin_amdgcn_global_load_lds(                                  \
      (const __attribute__((address_space(1))) unsigned int*)(gp),   \
      (__attribute__((address_space(3))) unsigned int*)(lp), 16, 0, 0)

// ws layout (floats): ex_m [NB*RB*WB], ey_m [NB*RB*HB]
__global__ void tables_kernel(const float* __restrict__ roi,
                              float* __restrict__ ws,
                              float* __restrict__ out_params) {
  const int nr = blockIdx.x;            // n*64 + r
  const int t  = threadIdx.x;           // 0..127

  const float mux = roi[nr * 4 + 0];
  const float muy = roi[nr * 4 + 1];
  const float sgx = roi[nr * 4 + 2];
  const float sgy = roi[nr * 4 + 3];

  const float g  = (t + 0.5f) * (1.0f / 128.0f);
  const float tx = fabsf(g - mux) / sgx;
  const float ty = fabsf(g - muy) / sgy;
  const float lx = -(tx * tx);          // BETA = 2.0
  const float ly = -(ty * ty);

  __shared__ float sdx[128], sdy[128];
  sdx[t] = lx; sdy[t] = ly;
  __syncthreads();
  for (int off = 64; off > 0; off >>= 1) {
    if (t < off) {
      sdx[t] = fmaxf(sdx[t], sdx[t + off]);
      sdy[t] = fmaxf(sdy[t], sdy[t + off]);
    }
    __syncthreads();
  }
  const float mlx = sdx[0], mly = sdy[0];

  const float em = expf(mlx + mly);             // == max over scores (separable)
  const float s  = em / (em + 1e-12f);
  const float exv = expf(lx - mlx);
  const float eyv = expf(ly - mly) * s;

  float* ex_m = ws;
  float* ey_m = ws + NB * RB * WB;
  ex_m[nr * WB + t] = exv;
  ey_m[nr * HB + t] = eyv;

  if (t < 4) out_params[nr * 4 + t] = roi[nr * 4 + t];
}

__global__ void map_kernel(const float* __restrict__ ws,
                           float* __restrict__ out_map) {
  const float* ex_m = ws;
  const float* ey_m = ws + NB * RB * WB;
  const int total = NB * RB * HB * WB / 4;      // float4 count
  for (int idx = blockIdx.x * blockDim.x + threadIdx.x; idx < total;
       idx += gridDim.x * blockDim.x) {
    const int w4 = idx & 31;                    // 32 float4 per row
    const int h  = (idx >> 5) & 127;
    const int nr = idx >> 12;
    const float  ey = ey_m[nr * HB + h];
    const float4 ex = *reinterpret_cast<const float4*>(ex_m + nr * WB + w4 * 4);
    float4 o;
    o.x = ey * ex.x; o.y = ey * ex.y; o.z = ey * ex.z; o.w = ey * ex.w;
    reinterpret_cast<float4*>(out_map)[idx] = o;
  }
}

// ---------- PROBE K1: raw register-streaming bandwidth at feat's occupancy ----
// Same grid/wave count as feat (512 blocks x 256 thr), no LDS, no barriers.
__global__ __launch_bounds__(256, 1) void bw_probe_kernel(
    const float* __restrict__ x, float* __restrict__ garbage) {
  const int bid = blockIdx.x;
  const int t   = threadIdx.x;
  const f32x4* p = reinterpret_cast<const f32x4*>(x) + (size_t)bid * 32768 + t;
  f32x4 s0 = (f32x4)0.0f, s1 = (f32x4)0.0f, s2 = (f32x4)0.0f, s3 = (f32x4)0.0f;
#pragma unroll 8
  for (int i = 0; i < 128; i += 4) {
    s0 += p[(size_t)(i + 0) * 256];
    s1 += p[(size_t)(i + 1) * 256];
    s2 += p[(size_t)(i + 2) * 256];
    s3 += p[(size_t)(i + 3) * 256];
  }
  reinterpret_cast<f32x4*>(garbage)[bid * 256 + t] = s0 + s1 + s2 + s3;
}

// ---------- PROBE K2: R5's staging skeleton (gload_lds + counted vmcnt +
// barriers + ds_read), minus A-build / cvt / MFMA / atomics. --------------
__global__ __launch_bounds__(256, 1) void stage_probe_kernel(
    const float* __restrict__ x, float* __restrict__ garbage) {
  __shared__ float buf[4][32 * DB];     // 128 KB (same as feat)

  const int bid = blockIdx.x;
  const int t   = threadIdx.x;
  const int l   = t & 63;
  const int wv  = t >> 6;
  const int l15 = l & 15;
  const int lk  = (l >> 4) * 8;

  const char* gx = (const char*)(x + (size_t)bid * 512 * DB);
  char* lbase = (char*)&buf[0][0];

  f32x4 vsum = (f32x4)0.0f;

#define PSTAGE(bi, slot) do {                                                \
    const char* gsrc_ = gx + (size_t)(bi) * 32768;                           \
    char* ldst_ = lbase + (slot) * 32768;                                    \
    _Pragma("unroll")                                                        \
    for (int ii = 0; ii < 8; ++ii)                                           \
      GLOAD_LDS16(gsrc_ + ii * 4096 + wv * 1024 + l * 16,                    \
                  ldst_ + ii * 4096 + wv * 1024);                            \
  } while (0)

  PSTAGE(0, 0); PSTAGE(1, 1); PSTAGE(2, 2);

#define PSTEP(bi, VM, DO_STAGE) do {                                         \
    asm volatile("s_waitcnt vmcnt(" #VM ")" ::: "memory");                   \
    __builtin_amdgcn_s_barrier();                                            \
    __builtin_amdgcn_sched_barrier(0);                                       \
    if (DO_STAGE) PSTAGE((bi) + 3, ((bi) + 3) & 3);                          \
    const float* bp_ = &buf[(bi) & 3][0];                                    \
    _Pragma("unroll")                                                        \
    for (int j = 0; j < 8; ++j)                                              \
      vsum += *reinterpret_cast<const f32x4*>(                               \
          bp_ + (lk + j) * DB + wv * 64 + l15 * 4);                          \
  } while (0)

  PSTEP(0, 16, 1);  PSTEP(1, 16, 1);  PSTEP(2, 16, 1);  PSTEP(3, 16, 1);
  PSTEP(4, 16, 1);  PSTEP(5, 16, 1);  PSTEP(6, 16, 1);  PSTEP(7, 16, 1);
  PSTEP(8, 16, 1);  PSTEP(9, 16, 1);  PSTEP(10, 16, 1); PSTEP(11, 16, 1);
  PSTEP(12, 16, 1); PSTEP(13, 16, 0); PSTEP(14, 8, 0);  PSTEP(15, 0, 0);

#undef PSTEP
#undef PSTAGE

  reinterpret_cast<f32x4*>(garbage)[bid * 256 + t] = vsum;
}

// feat v5 (unchanged from R5): counted-vmcnt pipelined split-K GEMM.
__global__ __launch_bounds__(256, 1) void feat_mfma_kernel(
    const float* __restrict__ x, const float* __restrict__ ws, float* outF) {
  __shared__ float buf[4][32 * DB];     // 128 KB

  const float* ex_m = ws;
  const float* ey_m = ws + NB * RB * WB;

  const int bid = blockIdx.x;
  const int n   = bid >> 5;
  const int kc  = bid & 31;
  const int t   = threadIdx.x;
  const int l   = t & 63;
  const int wv  = t >> 6;
  const int l15 = l & 15;
  const int lk  = (l >> 4) * 8;         // lane's k-offset within a k-step
  const int h0  = kc * 4;               // first h-row of this chunk

  const char* gx =
      (const char*)(x + ((size_t)n * HW + (size_t)kc * 512) * DB);
  char* lbase = (char*)&buf[0][0];

  // ---- prologue 1: table values into registers, drained before staging ----
  f32x4 exr[4][4][2];                   // [rf][ks][half]
  float eyv[4][4];                      // [hh][rf]
#pragma unroll
  for (int rf = 0; rf < 4; ++rf) {
    const float* exrow = ex_m + (size_t)(n * RB + rf * 16 + l15) * WB;
#pragma unroll
    for (int ks = 0; ks < 4; ++ks) {
      exr[rf][ks][0] = *reinterpret_cast<const f32x4*>(exrow + ks * 32 + lk);
      exr[rf][ks][1] = *reinterpret_cast<const f32x4*>(exrow + ks * 32 + lk + 4);
    }
  }
#pragma unroll
  for (int hh = 0; hh < 4; ++hh)
#pragma unroll
    for (int rf = 0; rf < 4; ++rf)
      eyv[hh][rf] = ey_m[(size_t)(n * RB + rf * 16 + l15) * HB + h0 + hh];
  asm volatile("s_waitcnt vmcnt(0)" ::: "memory");

  f32x4 acc[4][4];
#pragma unroll
  for (int rf = 0; rf < 4; ++rf)
#pragma unroll
    for (int f = 0; f < 4; ++f) acc[rf][f] = (f32x4)0.0f;

#define STAGE(bi, slot) do {                                                 \
    const char* gsrc_ = gx + (size_t)(bi) * 32768;                           \
    char* ldst_ = lbase + (slot) * 32768;                                    \
    _Pragma("unroll")                                                        \
    for (int ii = 0; ii < 8; ++ii)                                           \
      GLOAD_LDS16(gsrc_ + ii * 4096 + wv * 1024 + l * 16,                    \
                  ldst_ + ii * 4096 + wv * 1024);                            \
  } while (0)

  STAGE(0, 0); STAGE(1, 1); STAGE(2, 2);

#define KSTEP(bi, VM, DO_STAGE) do {                                         \
    asm volatile("s_waitcnt vmcnt(" #VM ")" ::: "memory");                   \
    __builtin_amdgcn_s_barrier();                                            \
    __builtin_amdgcn_sched_barrier(0);                                       \
    if (DO_STAGE) STAGE((bi) + 3, ((bi) + 3) & 3);                           \
    const float* bp_ = &buf[(bi) & 3][0];                                    \
    f32x4 xv_[8];                                                            \
    _Pragma("unroll")                                                        \
    for (int j = 0; j < 8; ++j)                                              \
      xv_[j] = *reinterpret_cast<const f32x4*>(                              \
          bp_ + (lk + j) * DB + wv * 64 + l15 * 4);                          \
    bf16x8 bfr_[4];                                                          \
    _Pragma("unroll")                                                        \
    for (int f = 0; f < 4; ++f) {                                            \
      bf16x8 b_;                                                             \
      _Pragma("unroll")                                                      \
      for (int j = 0; j < 8; ++j) b_[j] = f2bf(xv_[j][f]);                   \
      bfr_[f] = b_;                                                          \
    }                                                                        \
    bf16x8 afr_[4];                                                          \
    _Pragma("unroll")                                                        \
    for (int rf = 0; rf < 4; ++rf) {                                         \
      const float ey_ = eyv[(bi) >> 2][rf];                                  \
      const f32x4 e0_ = exr[rf][(bi) & 3][0];                                \
      const f32x4 e1_ = exr[rf][(bi) & 3][1];                                \
      bf16x8 a_;                                                             \
      a_[0] = f2bf(ey_ * e0_.x); a_[1] = f2bf(ey_ * e0_.y);                  \
      a_[2] = f2bf(ey_ * e0_.z); a_[3] = f2bf(ey_ * e0_.w);                  \
      a_[4] = f2bf(ey_ * e1_.x); a_[5] = f2bf(ey_ * e1_.y);                  \
      a_[6] = f2bf(ey_ * e1_.z); a_[7] = f2bf(ey_ * e1_.w);                  \
      afr_[rf] = a_;                                                         \
    }                                                                        \
    _Pragma("unroll")                                                        \
    for (int rf = 0; rf < 4; ++rf)                                           \
      _Pragma("unroll")                                                      \
      for (int f = 0; f < 4; ++f)                                            \
        acc[rf][f] = __builtin_amdgcn_mfma_f32_16x16x32_bf16(                \
            afr_[rf], bfr_[f], acc[rf][f], 0, 0, 0);                         \
  } while (0)

  KSTEP(0, 16, 1);  KSTEP(1, 16, 1);  KSTEP(2, 16, 1);  KSTEP(3, 16, 1);
  KSTEP(4, 16, 1);  KSTEP(5, 16, 1);  KSTEP(6, 16, 1);  KSTEP(7, 16, 1);
  KSTEP(8, 16, 1);  KSTEP(9, 16, 1);  KSTEP(10, 16, 1); KSTEP(11, 16, 1);
  KSTEP(12, 16, 1); KSTEP(13, 16, 0); KSTEP(14, 8, 0);  KSTEP(15, 0, 0);

#undef KSTEP
#undef STAGE

  const float sc = 1.0f / (float)HW;
#pragma unroll
  for (int rf = 0; rf < 4; ++rf) {
#pragma unroll
    for (int f = 0; f < 4; ++f) {
#pragma unroll
      for (int reg = 0; reg < 4; ++reg) {
        const int r = rf * 16 + (l >> 4) * 4 + reg;
        const int d = wv * 64 + l15 * 4 + f;
        atomicAdd(outF + (size_t)(n * RB + r) * DB + d, acc[rf][f][reg] * sc);
      }
    }
  }
}

extern "C" void kernel_launch(void* const* d_in, const int* in_sizes, int n_in,
                              void* d_out, int out_size, void* d_ws, size_t ws_size,
                              hipStream_t stream) {
  const float* x   = (const float*)d_in[0];
  const float* roi = (const float*)d_in[1];
  float* out        = (float*)d_out;
  float* ws         = (float*)d_ws;      // 2 * 131072 floats = 1 MB
  float* out_feat   = out;                         // 16*64*256
  float* out_params = out + NB * RB * DB;          // 16*64*4
  float* out_map    = out_params + NB * RB * 4;    // 16*64*128*128

  // ---- ablation probes: scribble into out_map region, which map_kernel
  // fully overwrites afterwards (final output stays correct) ----
  bw_probe_kernel<<<512, 256, 0, stream>>>(x, out_map);
  stage_probe_kernel<<<512, 256, 0, stream>>>(x, out_map + 1024 * 1024);

  // features accumulate via atomics -> zero every call (deterministic)
  hipMemsetAsync(out_feat, 0, (size_t)NB * RB * DB * sizeof(float), stream);

  tables_kernel<<<NB * RB, 128, 0, stream>>>(roi, ws, out_params);
  feat_mfma_kernel<<<512, 256, 0, stream>>>(x, ws, out_feat);
  map_kernel<<<2048, 256, 0, stream>>>(ws, out_map);
}

// Round 7
// 95.036 us; speedup vs baseline: 2.7568x; 2.7568x over previous
//
#include <hip/hip_runtime.h>
#include <hip/hip_bf16.h>
#include <math.h>

#define NB 16
#define RB 64
#define HB 128
#define WB 128
#define DB 256
#define HW (HB * WB)

typedef __attribute__((ext_vector_type(8))) short bf16x8;
typedef __attribute__((ext_vector_type(4))) float f32x4;

static __device__ __forceinline__ short f2bf(float f) {
  __hip_bfloat16 h = __float2bfloat16(f);
  return *reinterpret_cast<short*>(&h);
}

// async global->LDS, 16B per lane: HW writes wave-uniform LDS base + lane*16
#define GLOAD_LDS16(gp, lp)                                          \
  __builtin_amdgcn_global_load_lds(                                  \
      (const __attribute__((address_space(1))) unsigned int*)(gp),   \
      (__attribute__((address_space(3))) unsigned int*)(lp), 16, 0, 0)

// ws layout (floats): ex_m [NB*RB*WB], ey_m [NB*RB*HB]
__global__ void tables_kernel(const float* __restrict__ roi,
                              float* __restrict__ ws,
                              float* __restrict__ out_params) {
  const int nr = blockIdx.x;            // n*64 + r
  const int t  = threadIdx.x;           // 0..127

  const float mux = roi[nr * 4 + 0];
  const float muy = roi[nr * 4 + 1];
  const float sgx = roi[nr * 4 + 2];
  const float sgy = roi[nr * 4 + 3];

  const float g  = (t + 0.5f) * (1.0f / 128.0f);
  const float tx = fabsf(g - mux) / sgx;
  const float ty = fabsf(g - muy) / sgy;
  const float lx = -(tx * tx);          // BETA = 2.0
  const float ly = -(ty * ty);

  __shared__ float sdx[128], sdy[128];
  sdx[t] = lx; sdy[t] = ly;
  __syncthreads();
  for (int off = 64; off > 0; off >>= 1) {
    if (t < off) {
      sdx[t] = fmaxf(sdx[t], sdx[t + off]);
      sdy[t] = fmaxf(sdy[t], sdy[t + off]);
    }
    __syncthreads();
  }
  const float mlx = sdx[0], mly = sdy[0];

  const float em = expf(mlx + mly);             // == max over scores (separable)
  const float s  = em / (em + 1e-12f);
  const float exv = expf(lx - mlx);
  const float eyv = expf(ly - mly) * s;

  float* ex_m = ws;
  float* ey_m = ws + NB * RB * WB;
  ex_m[nr * WB + t] = exv;
  ey_m[nr * HB + t] = eyv;

  if (t < 4) out_params[nr * 4 + t] = roi[nr * 4 + t];
}

__global__ void map_kernel(const float* __restrict__ ws,
                           float* __restrict__ out_map) {
  const float* ex_m = ws;
  const float* ey_m = ws + NB * RB * WB;
  const int total = NB * RB * HB * WB / 4;      // float4 count
  for (int idx = blockIdx.x * blockDim.x + threadIdx.x; idx < total;
       idx += gridDim.x * blockDim.x) {
    const int w4 = idx & 31;                    // 32 float4 per row
    const int h  = (idx >> 5) & 127;
    const int nr = idx >> 12;
    const float  ey = ey_m[nr * HB + h];
    const float4 ex = *reinterpret_cast<const float4*>(ex_m + nr * WB + w4 * 4);
    float4 o;
    o.x = ey * ex.x; o.y = ey * ex.y; o.z = ey * ex.z; o.w = ey * ex.w;
    reinterpret_cast<float4*>(out_map)[idx] = o;
  }
}

// feat v6: R5's counted-vmcnt pipeline, ATOMIC-FREE epilogue.
// Each block writes its 64KB partial tile P[bid][64][256] with plain
// coalesced stores; reduce_kernel sums the 32 kc-partials per image.
__global__ __launch_bounds__(256, 1) void feat_mfma_kernel(
    const float* __restrict__ x, const float* __restrict__ ws,
    float* __restrict__ partials) {
  __shared__ float buf[4][32 * DB];     // 128 KB

  const float* ex_m = ws;
  const float* ey_m = ws + NB * RB * WB;

  const int bid = blockIdx.x;
  const int n   = bid >> 5;
  const int kc  = bid & 31;
  const int t   = threadIdx.x;
  const int l   = t & 63;
  const int wv  = t >> 6;
  const int l15 = l & 15;
  const int lk  = (l >> 4) * 8;         // lane's k-offset within a k-step
  const int h0  = kc * 4;               // first h-row of this chunk

  const char* gx =
      (const char*)(x + ((size_t)n * HW + (size_t)kc * 512) * DB);
  char* lbase = (char*)&buf[0][0];

  // ---- prologue 1: table values into registers, drained before staging ----
  f32x4 exr[4][4][2];                   // [rf][ks][half]
  float eyv[4][4];                      // [hh][rf]
#pragma unroll
  for (int rf = 0; rf < 4; ++rf) {
    const float* exrow = ex_m + (size_t)(n * RB + rf * 16 + l15) * WB;
#pragma unroll
    for (int ks = 0; ks < 4; ++ks) {
      exr[rf][ks][0] = *reinterpret_cast<const f32x4*>(exrow + ks * 32 + lk);
      exr[rf][ks][1] = *reinterpret_cast<const f32x4*>(exrow + ks * 32 + lk + 4);
    }
  }
#pragma unroll
  for (int hh = 0; hh < 4; ++hh)
#pragma unroll
    for (int rf = 0; rf < 4; ++rf)
      eyv[hh][rf] = ey_m[(size_t)(n * RB + rf * 16 + l15) * HB + h0 + hh];
  asm volatile("s_waitcnt vmcnt(0)" ::: "memory");  // vmcnt now tracks staging only

  f32x4 acc[4][4];
#pragma unroll
  for (int rf = 0; rf < 4; ++rf)
#pragma unroll
    for (int f = 0; f < 4; ++f) acc[rf][f] = (f32x4)0.0f;

#define STAGE(bi, slot) do {                                                 \
    const char* gsrc_ = gx + (size_t)(bi) * 32768;                           \
    char* ldst_ = lbase + (slot) * 32768;                                    \
    _Pragma("unroll")                                                        \
    for (int ii = 0; ii < 8; ++ii)                                           \
      GLOAD_LDS16(gsrc_ + ii * 4096 + wv * 1024 + l * 16,                    \
                  ldst_ + ii * 4096 + wv * 1024);                            \
  } while (0)

  STAGE(0, 0); STAGE(1, 1); STAGE(2, 2);

#define KSTEP(bi, VM, DO_STAGE) do {                                         \
    asm volatile("s_waitcnt vmcnt(" #VM ")" ::: "memory");                   \
    __builtin_amdgcn_s_barrier();                                            \
    __builtin_amdgcn_sched_barrier(0);                                       \
    if (DO_STAGE) STAGE((bi) + 3, ((bi) + 3) & 3);                           \
    const float* bp_ = &buf[(bi) & 3][0];                                    \
    f32x4 xv_[8];                                                            \
    _Pragma("unroll")                                                        \
    for (int j = 0; j < 8; ++j)                                              \
      xv_[j] = *reinterpret_cast<const f32x4*>(                              \
          bp_ + (lk + j) * DB + wv * 64 + l15 * 4);                          \
    bf16x8 bfr_[4];                                                          \
    _Pragma("unroll")                                                        \
    for (int f = 0; f < 4; ++f) {                                            \
      bf16x8 b_;                                                             \
      _Pragma("unroll")                                                      \
      for (int j = 0; j < 8; ++j) b_[j] = f2bf(xv_[j][f]);                   \
      bfr_[f] = b_;                                                          \
    }                                                                        \
    bf16x8 afr_[4];                                                          \
    _Pragma("unroll")                                                        \
    for (int rf = 0; rf < 4; ++rf) {                                         \
      const float ey_ = eyv[(bi) >> 2][rf];                                  \
      const f32x4 e0_ = exr[rf][(bi) & 3][0];                                \
      const f32x4 e1_ = exr[rf][(bi) & 3][1];                                \
      bf16x8 a_;                                                             \
      a_[0] = f2bf(ey_ * e0_.x); a_[1] = f2bf(ey_ * e0_.y);                  \
      a_[2] = f2bf(ey_ * e0_.z); a_[3] = f2bf(ey_ * e0_.w);                  \
      a_[4] = f2bf(ey_ * e1_.x); a_[5] = f2bf(ey_ * e1_.y);                  \
      a_[6] = f2bf(ey_ * e1_.z); a_[7] = f2bf(ey_ * e1_.w);                  \
      afr_[rf] = a_;                                                         \
    }                                                                        \
    _Pragma("unroll")                                                        \
    for (int rf = 0; rf < 4; ++rf)                                           \
      _Pragma("unroll")                                                      \
      for (int f = 0; f < 4; ++f)                                            \
        acc[rf][f] = __builtin_amdgcn_mfma_f32_16x16x32_bf16(                \
            afr_[rf], bfr_[f], acc[rf][f], 0, 0, 0);                         \
  } while (0)

  KSTEP(0, 16, 1);  KSTEP(1, 16, 1);  KSTEP(2, 16, 1);  KSTEP(3, 16, 1);
  KSTEP(4, 16, 1);  KSTEP(5, 16, 1);  KSTEP(6, 16, 1);  KSTEP(7, 16, 1);
  KSTEP(8, 16, 1);  KSTEP(9, 16, 1);  KSTEP(10, 16, 1); KSTEP(11, 16, 1);
  KSTEP(12, 16, 1); KSTEP(13, 16, 0); KSTEP(14, 8, 0);  KSTEP(15, 0, 0);

#undef KSTEP
#undef STAGE

  // ---- epilogue: plain coalesced stores of the partial tile (no atomics).
  // D layout: col = lane&15 (-> d, +f over vector), row = (lane>>4)*4 + reg.
  float* P = partials + (size_t)bid * (RB * DB);
#pragma unroll
  for (int rf = 0; rf < 4; ++rf) {
#pragma unroll
    for (int reg = 0; reg < 4; ++reg) {
      const int r = rf * 16 + (l >> 4) * 4 + reg;
      f32x4 v;
      v.x = acc[rf][0][reg]; v.y = acc[rf][1][reg];
      v.z = acc[rf][2][reg]; v.w = acc[rf][3][reg];
      *reinterpret_cast<f32x4*>(P + (size_t)r * DB + wv * 64 + l15 * 4) = v;
    }
  }
}

// Sum the 32 kc-partials per image; apply 1/HW. 65536 f32x4 outputs.
__global__ __launch_bounds__(256) void reduce_kernel(
    const float* __restrict__ partials, float* __restrict__ outF) {
  const int idx = blockIdx.x * 256 + threadIdx.x;   // f32x4 index
  const int n   = idx >> 12;                        // 4096 f32x4 per image
  const int i4  = idx & 4095;
  const f32x4* p =
      reinterpret_cast<const f32x4*>(partials) + (size_t)n * 32 * 4096 + i4;
  f32x4 s0 = (f32x4)0.0f, s1 = (f32x4)0.0f, s2 = (f32x4)0.0f, s3 = (f32x4)0.0f;
#pragma unroll
  for (int kc = 0; kc < 32; kc += 4) {
    s0 += p[(size_t)(kc + 0) * 4096];
    s1 += p[(size_t)(kc + 1) * 4096];
    s2 += p[(size_t)(kc + 2) * 4096];
    s3 += p[(size_t)(kc + 3) * 4096];
  }
  f32x4 s = (s0 + s1) + (s2 + s3);
  s *= (1.0f / (float)HW);
  reinterpret_cast<f32x4*>(outF)[idx] = s;
}

extern "C" void kernel_launch(void* const* d_in, const int* in_sizes, int n_in,
                              void* d_out, int out_size, void* d_ws, size_t ws_size,
                              hipStream_t stream) {
  const float* x   = (const float*)d_in[0];
  const float* roi = (const float*)d_in[1];
  float* out        = (float*)d_out;
  float* ws         = (float*)d_ws;      // 2 * 131072 floats = 1 MB
  float* out_feat   = out;                         // 16*64*256
  float* out_params = out + NB * RB * DB;          // 16*64*4
  float* out_map    = out_params + NB * RB * 4;    // 16*64*128*128 (67 MB)

  // Partials (512 x 64KB = 32MB) live at the head of the out_map region;
  // map_kernel fully overwrites it afterwards (stream-ordered, deterministic).
  float* P = out_map;

  tables_kernel<<<NB * RB, 128, 0, stream>>>(roi, ws, out_params);
  feat_mfma_kernel<<<512, 256, 0, stream>>>(x, ws, P);
  reduce_kernel<<<256, 256, 0, stream>>>(P, out_feat);
  map_kernel<<<2048, 256, 0, stream>>>(ws, out_map);
}